// Round 6
// baseline (383.885 us; speedup 1.0000x reference)
//
#include <hip/hip_runtime.h>

typedef short short8 __attribute__((ext_vector_type(8)));
typedef short short4v __attribute__((ext_vector_type(4)));
typedef float floatx4 __attribute__((ext_vector_type(4)));
typedef unsigned short ushort_t;

#define EMBED 1024
#define HEADS 16
#define HD 64
#define SEQ 2048
#define BATCH 2
#define QSCALE 0.18033688f   // log2(e) / sqrt(64), folded into Q at GEMM epilogue

__device__ inline ushort_t f2bf(float f) {
    unsigned int u = __float_as_uint(f);
    u += 0x7fff + ((u >> 16) & 1);   // round-to-nearest-even
    return (ushort_t)(u >> 16);
}

// async global->LDS, 16B per lane. LDS dest = wave-uniform base + lane*16.
typedef const __attribute__((address_space(1))) unsigned int* gas_t;
typedef __attribute__((address_space(3))) unsigned int* las_t;
__device__ inline void async_copy16(const ushort_t* g, ushort_t* l) {
    __builtin_amdgcn_global_load_lds((gas_t)g, (las_t)l, 16, 0, 0);
}

// ---------------- fused cast fp32 -> bf16 (3 tensors, 1 launch) -----------
__global__ void cast3_kernel(const float* __restrict__ a, ushort_t* __restrict__ oa, int na,
                             const float* __restrict__ b, ushort_t* __restrict__ ob, int nb,
                             const float* __restrict__ c, ushort_t* __restrict__ oc, int nc) {
    int idx = (blockIdx.x * blockDim.x + threadIdx.x) * 4;
    const float* in; ushort_t* out;
    if (idx < na)            { in = a;  out = oa; }
    else if (idx < na + nb)  { in = b;  out = ob; idx -= na; }
    else if (idx < na + nb + nc) { in = c; out = oc; idx -= na + nb; }
    else return;
    float4 f = *(const float4*)(in + idx);
    ushort4 o;
    o.x = f2bf(f.x); o.y = f2bf(f.y); o.z = f2bf(f.z); o.w = f2bf(f.w);
    *(ushort4*)(out + idx) = o;
}

// ---------------- GEMM (BK=64, XCD swizzle): Y = A * B^T ------------------
// TBN=128 for the big QKV GEMM; TBN=64 for the out-proj (512 blocks = 2/CU).
#define BM 128
#define BK 64

template<int MODE, int TBN>
__launch_bounds__(256, 3)
__global__ void gemm_bt(const ushort_t* __restrict__ A, const ushort_t* __restrict__ B,
                        float* __restrict__ outF,
                        ushort_t* __restrict__ qb, ushort_t* __restrict__ kb,
                        ushort_t* __restrict__ vtb,
                        int M, int N, int K) {
    __shared__ ushort_t As[BM * BK];    // 16KB, unpadded (DMA dest), XOR-swizzled granules
    __shared__ ushort_t Bs[TBN * BK];   // 16KB or 8KB
    const int id   = blockIdx.x;
    const int jj   = id >> 3;
    const int bm   = (id & 7) * 4 + (jj & 3);   // 4 m-blocks per XCD
    const int bn   = jj >> 2;
    const int t    = threadIdx.x;
    const int lane = t & 63;
    const int wave = t >> 6;
    const int wm   = (wave >> 1) * 64;
    const int wn   = (wave & 1) * (TBN / 2);
    const int m0   = bm * BM;
    const int n0   = bn * TBN;
    const int col  = lane & 15;
    const int quad = lane >> 4;
    constexpr int NJ = TBN / 32;

    const int srow = lane >> 3;
    const int sgr  = (lane & 7) ^ (srow & 7);
    const int slot0 = quad ^ (col & 7);          // granules 0..3  (k 0..31)

    floatx4 acc[4][NJ] = {};

    for (int k0 = 0; k0 < K; k0 += BK) {
        for (int half = 0; half < 4; ++half) {
            int row0 = wave * 32 + half * 8;
            int r = row0 + srow;
            async_copy16(A + (size_t)(m0 + r) * K + k0 + sgr * 8, &As[row0 * BK]);
        }
        for (int half = 0; half < TBN / 32; ++half) {
            int row0 = wave * (TBN / 4) + half * 8;
            int r = row0 + srow;
            async_copy16(B + (size_t)(n0 + r) * K + k0 + sgr * 8, &Bs[row0 * BK]);
        }
        __syncthreads();
        short8 a[2][4], b[2][NJ];
        for (int i = 0; i < 4; ++i) {
            int base = (wm + i * 16 + col) * BK;
            a[0][i] = *(const short8*)(&As[base + slot0 * 8]);
            a[1][i] = *(const short8*)(&As[base + (slot0 ^ 4) * 8]);
        }
        for (int j = 0; j < NJ; ++j) {
            int base = (wn + j * 16 + col) * BK;
            b[0][j] = *(const short8*)(&Bs[base + slot0 * 8]);
            b[1][j] = *(const short8*)(&Bs[base + (slot0 ^ 4) * 8]);
        }
        for (int kk = 0; kk < 2; ++kk)
            for (int i = 0; i < 4; ++i)
                for (int j = 0; j < NJ; ++j)
                    acc[i][j] = __builtin_amdgcn_mfma_f32_16x16x32_bf16(a[kk][i], b[kk][j], acc[i][j], 0, 0, 0);
        __syncthreads();
    }

    for (int i = 0; i < 4; ++i)
        for (int j = 0; j < NJ; ++j) {
            int n = n0 + wn + j * 16 + col;
            int mb = m0 + wm + i * 16 + quad * 4;   // 4 consecutive m
            if (MODE == 1) {
                for (int r = 0; r < 4; ++r)
                    outF[(size_t)(mb + r) * N + n] = acc[i][j][r];
            } else {
                int part = n >> 10;          // 0=q 1=k 2=v
                int within = n & 1023;
                int h = within >> 6, d = within & 63;
                int bb = mb >> 11, s = mb & 2047;
                if (part == 2) {
                    short4v pv;
                    pv.x = (short)f2bf(acc[i][j][0]); pv.y = (short)f2bf(acc[i][j][1]);
                    pv.z = (short)f2bf(acc[i][j][2]); pv.w = (short)f2bf(acc[i][j][3]);
                    *(short4v*)(vtb + (((size_t)bb * HEADS + h) * HD + d) * SEQ + s) = pv;
                } else {
                    ushort_t* dst = (part == 0) ? qb : kb;
                    const float scl = (part == 0) ? QSCALE : 1.0f;  // pre-scale Q
                    for (int r = 0; r < 4; ++r)
                        dst[(((size_t)bb * HEADS + h) * SEQ + s + r) * HD + d] = f2bf(acc[i][j][r] * scl);
                }
            }
        }
}

// ---------------- flash-style attention v12: 64 q/wave --------------------
// 256 blocks x 512 threads, exactly 1 block/CU. 2 kt-groups of 4 waves,
// each wave owns 64 q (4 qt tiles). kf/vf LDS reads are q-independent, so
// doubling q/wave halves total LDS read+DMA work per unit of MFMA work
// (4MB -> 2MB reads/CU) and amortizes per-iteration addressing VALU.
// Same x32-everything inner math as v11 (interleaved-key QK tiles -> verbatim
// x32 PV B-fragments; lsum via ones-MFMA).
// LDS 64KB: K[2grp][2buf][64x64] 32K + V[2grp][2buf][64x64] 32K.
__launch_bounds__(512, 2)
__global__ void attn_kernel(const ushort_t* __restrict__ qb_, const ushort_t* __restrict__ kb,
                            const ushort_t* __restrict__ vtb, ushort_t* __restrict__ attn) {
    __shared__ __align__(16) ushort_t lds[32768];  // 64KB
    const int id   = blockIdx.x;             // 256 blocks
    const int jj   = id >> 3;                // 0..31
    const int bh   = (id & 7) * 4 + (jj >> 3);   // 4 bh per XCD (K/V 2MB/XCD in L2)
    const int qblk = jj & 7;                 // 8 x 256-q tiles
    const int t    = threadIdx.x;
    const int lane = t & 63;
    const int wave = t >> 6;                 // 0..7
    const int g    = wave >> 2;              // kt group
    const int wv   = wave & 3;
    const int col  = lane & 15;
    const int quad = lane >> 4;
    const int q0   = qblk * 256 + wv * 64;
    const int srow = lane >> 3;
    const int sgr  = lane & 7;

    auto swz = [](int r) { return (r & 7) ^ ((r >> 1) & 4) ^ ((r >> 3) & 2); };

    const ushort_t* Q  = qb_ + (size_t)bh * SEQ * HD;
    const ushort_t* Kp = kb  + (size_t)bh * SEQ * HD;
    const ushort_t* Vt = vtb + (size_t)bh * HD * SEQ;

    ushort_t* Kb0 = &lds[g * 8192];            // this group's K double-buffer
    ushort_t* Vb0 = &lds[16384 + g * 8192];    // this group's V double-buffer

    auto stage = [&](int c, int buf) {
        int kt = c << 6;
        #pragma unroll
        for (int inst = 0; inst < 2; ++inst) {
            int row0 = wv * 16 + inst * 8;
            int r = row0 + srow;
            int gr = sgr ^ swz(r);
            async_copy16(Kp + (size_t)(kt + r) * HD + gr * 8,
                         Kb0 + buf * 4096 + row0 * 64);
            async_copy16(Vt + (size_t)r * SEQ + kt + gr * 8,
                         Vb0 + buf * 4096 + row0 * 64);
        }
    };

    short8 qf[4][2];
    #pragma unroll
    for (int qt = 0; qt < 4; ++qt) {
        qf[qt][0] = *(const short8*)(Q + (size_t)(q0 + qt * 16 + col) * HD + quad * 8);
        qf[qt][1] = *(const short8*)(Q + (size_t)(q0 + qt * 16 + col) * HD + 32 + quad * 8);
    }

    const short8 ones8 = { (short)0x3F80, (short)0x3F80, (short)0x3F80, (short)0x3F80,
                           (short)0x3F80, (short)0x3F80, (short)0x3F80, (short)0x3F80 };

    floatx4 acc[4][4] = {};          // [qt][dt]: row=d (quad*4+reg), col=q (lane&15)
    floatx4 accl[4] = {};            // lsum via ones-MFMA: all rows = sum_k P[k][q]

    stage(g, 0);                // group g starts at chunk g
    __syncthreads();

    for (int i = 0; i < 16; ++i) {
        const int cur = i & 1;
        if (i < 15) stage(2 * (i + 1) + g, cur ^ 1);  // async prefetch, drains at barrier
        const ushort_t* Kc = Kb0 + cur * 4096;
        const ushort_t* Vc = Vb0 + cur * 4096;

        #pragma unroll
        for (int h = 0; h < 2; ++h) {                 // 32-key halves of the 64-key chunk
            short8 kf[2][2], vf8[4];
            #pragma unroll
            for (int nl = 0; nl < 2; ++nl) {
                // interleaved key assignment: tile nl, lane col -> key-in-half
                int krow = h * 32 + ((col >> 2) << 3) + (col & 3) + nl * 4;
                int sk = swz(krow);
                kf[nl][0] = *(const short8*)(Kc + krow * 64 + ((quad ^ sk) * 8));
                kf[nl][1] = *(const short8*)(Kc + krow * 64 + (((4 + quad) ^ sk) * 8));
            }
            #pragma unroll
            for (int dt = 0; dt < 4; ++dt) {
                int vrow = dt * 16 + col;
                vf8[dt] = *(const short8*)(Vc + vrow * 64 + (((h * 4 + quad) ^ swz(vrow)) * 8));
            }
            #pragma unroll
            for (int qt = 0; qt < 4; ++qt) {
                unsigned pk[4];
                #pragma unroll
                for (int nl = 0; nl < 2; ++nl) {
                    floatx4 z = {};
                    __builtin_amdgcn_s_setprio(1);
                    z = __builtin_amdgcn_mfma_f32_16x16x32_bf16(kf[nl][0], qf[qt][0], z, 0, 0, 0);
                    z = __builtin_amdgcn_mfma_f32_16x16x32_bf16(kf[nl][1], qf[qt][1], z, 0, 0, 0);
                    __builtin_amdgcn_s_setprio(0);
                    // Q pre-scaled by QSCALE -> exp2 direct; truncate to bf16.
                    unsigned u0 = __float_as_uint(__builtin_amdgcn_exp2f(z[0]));
                    unsigned u1 = __float_as_uint(__builtin_amdgcn_exp2f(z[1]));
                    unsigned u2 = __float_as_uint(__builtin_amdgcn_exp2f(z[2]));
                    unsigned u3 = __float_as_uint(__builtin_amdgcn_exp2f(z[3]));
                    pk[nl * 2 + 0] = __builtin_amdgcn_perm(u1, u0, 0x07060302u);  // k=8q+{0,1}(+4nl)
                    pk[nl * 2 + 1] = __builtin_amdgcn_perm(u3, u2, 0x07060302u);  // k=8q+{2,3}(+4nl)
                }
                short8 pb8 = *(short8*)pk;       // x32 B-fragment, verbatim (k=quad*8+j)
                __builtin_amdgcn_s_setprio(1);
                accl[qt] = __builtin_amdgcn_mfma_f32_16x16x32_bf16(
                    ones8, pb8, accl[qt], 0, 0, 0);          // lsum in matrix pipe
                #pragma unroll
                for (int dt = 0; dt < 4; ++dt)
                    acc[qt][dt] = __builtin_amdgcn_mfma_f32_16x16x32_bf16(
                        vf8[dt], pb8, acc[qt][dt], 0, 0, 0);
                __builtin_amdgcn_s_setprio(0);
            }
        }
        __syncthreads();   // drains prefetch DMA + all waves' reads of cur buffers
    }

    // ---- cross-group combine: 2 rounds; each wave keeps qt {2g, 2g+1} ------
    float* fs = (float*)lds;
    const int slot  = (wave * 64 + lane) * 20;    // 8*64*20 floats = 40KB <= 64KB
    const int pslot = ((wave ^ 4) * 64 + lane) * 20;
    floatx4 accK[2][4];
    float lsK[2];
    #pragma unroll
    for (int r2 = 0; r2 < 2; ++r2) {
        const int sendqt = (g == 0) ? 2 + r2 : r2;   // tile the partner keeps
        const int keepqt = 2 * g + r2;
        #pragma unroll
        for (int d = 0; d < 4; ++d)
            *(floatx4*)(&fs[slot + d * 4]) = acc[sendqt][d];
        fs[slot + 16] = accl[sendqt][0];
        __syncthreads();
        #pragma unroll
        for (int d = 0; d < 4; ++d)
            accK[r2][d] = acc[keepqt][d] + *(const floatx4*)(&fs[pslot + d * 4]);
        lsK[r2] = accl[keepqt][0] + fs[pslot + 16];
        __syncthreads();
    }

    int b = bh >> 4, hh = bh & 15;
    #pragma unroll
    for (int r2 = 0; r2 < 2; ++r2) {
        float inv = 1.0f / lsK[r2];                  // q = lane&15 for every acc element
        int row = q0 + (2 * g + r2) * 16 + col;
        #pragma unroll
        for (int dt = 0; dt < 4; ++dt) {
            short4v o;
            o.x = (short)f2bf(accK[r2][dt][0] * inv);
            o.y = (short)f2bf(accK[r2][dt][1] * inv);
            o.z = (short)f2bf(accK[r2][dt][2] * inv);
            o.w = (short)f2bf(accK[r2][dt][3] * inv);
            *(short4v*)(attn + ((size_t)b * SEQ + row) * EMBED + hh * HD + dt * 16 + quad * 4) = o;
        }
    }
}

// ---------------- launch ----------------
extern "C" void kernel_launch(void* const* d_in, const int* in_sizes, int n_in,
                              void* d_out, int out_size, void* d_ws, size_t ws_size,
                              hipStream_t stream) {
    const float* x     = (const float*)d_in[0];   // [2,2048,1024]
    const float* w_qkv = (const float*)d_in[1];   // [3072,1024]
    const float* w_out = (const float*)d_in[2];   // [1024,1024]
    float* out = (float*)d_out;                   // [2,2048,1024] fp32

    char* ws = (char*)d_ws;
    size_t off = 0;
    ushort_t* x_bf    = (ushort_t*)(ws + off); off += (size_t)BATCH * SEQ * EMBED * 2;
    ushort_t* wqkv_bf = (ushort_t*)(ws + off); off += (size_t)3 * EMBED * EMBED * 2;
    ushort_t* wout_bf = (ushort_t*)(ws + off); off += (size_t)EMBED * EMBED * 2;
    ushort_t* q_buf   = (ushort_t*)(ws + off); off += (size_t)BATCH * HEADS * SEQ * HD * 2;
    ushort_t* k_buf   = (ushort_t*)(ws + off); off += (size_t)BATCH * HEADS * SEQ * HD * 2;
    ushort_t* vt_buf  = (ushort_t*)(ws + off); off += (size_t)BATCH * HEADS * SEQ * HD * 2;
    ushort_t* attn_bf = (ushort_t*)(ws + off); off += (size_t)BATCH * SEQ * EMBED * 2;

    int n_x = BATCH * SEQ * EMBED, n_wq = 3 * EMBED * EMBED, n_wo = EMBED * EMBED;
    int n_all = n_x + n_wq + n_wo;
    cast3_kernel<<<n_all / 1024, 256, 0, stream>>>(x, x_bf, n_x, w_qkv, wqkv_bf, n_wq,
                                                   w_out, wout_bf, n_wo);

    // qkv = x @ w_qkv^T : M=4096, N=3072, K=1024 -> 32x24 = 768 blocks
    gemm_bt<0, 128><<<768, 256, 0, stream>>>(
        x_bf, wqkv_bf, nullptr, q_buf, k_buf, vt_buf, BATCH * SEQ, 3 * EMBED, EMBED);

    attn_kernel<<<256, 512, 0, stream>>>(q_buf, k_buf, vt_buf, attn_bf);

    // out = attn @ w_out^T : M=4096, N=1024, K=1024 -> 32x16 = 512 blocks (2/CU)
    gemm_bt<1, 64><<<512, 256, 0, stream>>>(
        attn_bf, wout_bf, out, nullptr, nullptr, nullptr, BATCH * SEQ, EMBED, EMBED);
}

// Round 7
// 165.449 us; speedup vs baseline: 2.3203x; 2.3203x over previous
//
#include <hip/hip_runtime.h>

typedef short short8 __attribute__((ext_vector_type(8)));
typedef short short4v __attribute__((ext_vector_type(4)));
typedef float floatx4 __attribute__((ext_vector_type(4)));
typedef unsigned short ushort_t;

#define EMBED 1024
#define HEADS 16
#define HD 64
#define SEQ 2048
#define BATCH 2
#define QSCALE 0.18033688f   // log2(e) / sqrt(64), folded into Q at GEMM epilogue

__device__ inline ushort_t f2bf(float f) {
    unsigned int u = __float_as_uint(f);
    u += 0x7fff + ((u >> 16) & 1);   // round-to-nearest-even
    return (ushort_t)(u >> 16);
}

// async global->LDS, 16B per lane. LDS dest = wave-uniform base + lane*16.
typedef const __attribute__((address_space(1))) unsigned int* gas_t;
typedef __attribute__((address_space(3))) unsigned int* las_t;
__device__ inline void async_copy16(const ushort_t* g, ushort_t* l) {
    __builtin_amdgcn_global_load_lds((gas_t)g, (las_t)l, 16, 0, 0);
}

// ---------------- fused cast fp32 -> bf16 (3 tensors, 1 launch) -----------
__global__ void cast3_kernel(const float* __restrict__ a, ushort_t* __restrict__ oa, int na,
                             const float* __restrict__ b, ushort_t* __restrict__ ob, int nb,
                             const float* __restrict__ c, ushort_t* __restrict__ oc, int nc) {
    int idx = (blockIdx.x * blockDim.x + threadIdx.x) * 4;
    const float* in; ushort_t* out;
    if (idx < na)            { in = a;  out = oa; }
    else if (idx < na + nb)  { in = b;  out = ob; idx -= na; }
    else if (idx < na + nb + nc) { in = c; out = oc; idx -= na + nb; }
    else return;
    float4 f = *(const float4*)(in + idx);
    ushort4 o;
    o.x = f2bf(f.x); o.y = f2bf(f.y); o.z = f2bf(f.z); o.w = f2bf(f.w);
    *(ushort4*)(out + idx) = o;
}

// ---------------- GEMM (BK=64, XCD swizzle): Y = A * B^T ------------------
// TBN=128 for the big QKV GEMM; TBN=64 for the out-proj (512 blocks = 2/CU).
#define BM 128
#define BK 64

template<int MODE, int TBN>
__launch_bounds__(256, 3)
__global__ void gemm_bt(const ushort_t* __restrict__ A, const ushort_t* __restrict__ B,
                        float* __restrict__ outF,
                        ushort_t* __restrict__ qb, ushort_t* __restrict__ kb,
                        ushort_t* __restrict__ vtb,
                        int M, int N, int K) {
    __shared__ ushort_t As[BM * BK];    // 16KB, unpadded (DMA dest), XOR-swizzled granules
    __shared__ ushort_t Bs[TBN * BK];   // 16KB or 8KB
    const int id   = blockIdx.x;
    const int jj   = id >> 3;
    const int bm   = (id & 7) * 4 + (jj & 3);   // 4 m-blocks per XCD
    const int bn   = jj >> 2;
    const int t    = threadIdx.x;
    const int lane = t & 63;
    const int wave = t >> 6;
    const int wm   = (wave >> 1) * 64;
    const int wn   = (wave & 1) * (TBN / 2);
    const int m0   = bm * BM;
    const int n0   = bn * TBN;
    const int col  = lane & 15;
    const int quad = lane >> 4;
    constexpr int NJ = TBN / 32;

    const int srow = lane >> 3;
    const int sgr  = (lane & 7) ^ (srow & 7);
    const int slot0 = quad ^ (col & 7);          // granules 0..3  (k 0..31)

    floatx4 acc[4][NJ] = {};

    for (int k0 = 0; k0 < K; k0 += BK) {
        for (int half = 0; half < 4; ++half) {
            int row0 = wave * 32 + half * 8;
            int r = row0 + srow;
            async_copy16(A + (size_t)(m0 + r) * K + k0 + sgr * 8, &As[row0 * BK]);
        }
        for (int half = 0; half < TBN / 32; ++half) {
            int row0 = wave * (TBN / 4) + half * 8;
            int r = row0 + srow;
            async_copy16(B + (size_t)(n0 + r) * K + k0 + sgr * 8, &Bs[row0 * BK]);
        }
        __syncthreads();
        short8 a[2][4], b[2][NJ];
        for (int i = 0; i < 4; ++i) {
            int base = (wm + i * 16 + col) * BK;
            a[0][i] = *(const short8*)(&As[base + slot0 * 8]);
            a[1][i] = *(const short8*)(&As[base + (slot0 ^ 4) * 8]);
        }
        for (int j = 0; j < NJ; ++j) {
            int base = (wn + j * 16 + col) * BK;
            b[0][j] = *(const short8*)(&Bs[base + slot0 * 8]);
            b[1][j] = *(const short8*)(&Bs[base + (slot0 ^ 4) * 8]);
        }
        for (int kk = 0; kk < 2; ++kk)
            for (int i = 0; i < 4; ++i)
                for (int j = 0; j < NJ; ++j)
                    acc[i][j] = __builtin_amdgcn_mfma_f32_16x16x32_bf16(a[kk][i], b[kk][j], acc[i][j], 0, 0, 0);
        __syncthreads();
    }

    for (int i = 0; i < 4; ++i)
        for (int j = 0; j < NJ; ++j) {
            int n = n0 + wn + j * 16 + col;
            int mb = m0 + wm + i * 16 + quad * 4;   // 4 consecutive m
            if (MODE == 1) {
                for (int r = 0; r < 4; ++r)
                    outF[(size_t)(mb + r) * N + n] = acc[i][j][r];
            } else {
                int part = n >> 10;          // 0=q 1=k 2=v
                int within = n & 1023;
                int h = within >> 6, d = within & 63;
                int bb = mb >> 11, s = mb & 2047;
                if (part == 2) {
                    short4v pv;
                    pv.x = (short)f2bf(acc[i][j][0]); pv.y = (short)f2bf(acc[i][j][1]);
                    pv.z = (short)f2bf(acc[i][j][2]); pv.w = (short)f2bf(acc[i][j][3]);
                    *(short4v*)(vtb + (((size_t)bb * HEADS + h) * HD + d) * SEQ + s) = pv;
                } else {
                    ushort_t* dst = (part == 0) ? qb : kb;
                    const float scl = (part == 0) ? QSCALE : 1.0f;  // pre-scale Q
                    for (int r = 0; r < 4; ++r)
                        dst[(((size_t)bb * HEADS + h) * SEQ + s + r) * HD + d] = f2bf(acc[i][j][r] * scl);
                }
            }
        }
}

// ---------------- flash-style attention v12b: 64 q/wave (spill fixed) -----
// 256 blocks x 512 threads, exactly 1 block/CU. 2 kt-groups of 4 waves,
// each wave owns 64 q (4 qt tiles). kf/vf LDS reads are q-independent, so
// doubling q/wave halves total LDS read+DMA work per unit of MFMA work.
// v12's combine indexed acc[] with a runtime (g-dependent) subscript ->
// the whole accumulator array was demoted to scratch (1.3GB HBM traffic,
// rule #20). v12b: wave-uniform if/else arms with compile-time-constant
// indices only.
// LDS 64KB: K[2grp][2buf][64x64] 32K + V[2grp][2buf][64x64] 32K.
__launch_bounds__(512, 2)
__global__ void attn_kernel(const ushort_t* __restrict__ qb_, const ushort_t* __restrict__ kb,
                            const ushort_t* __restrict__ vtb, ushort_t* __restrict__ attn) {
    __shared__ __align__(16) ushort_t lds[32768];  // 64KB
    const int id   = blockIdx.x;             // 256 blocks
    const int jj   = id >> 3;                // 0..31
    const int bh   = (id & 7) * 4 + (jj >> 3);   // 4 bh per XCD (K/V 2MB/XCD in L2)
    const int qblk = jj & 7;                 // 8 x 256-q tiles
    const int t    = threadIdx.x;
    const int lane = t & 63;
    const int wave = t >> 6;                 // 0..7
    const int g    = wave >> 2;              // kt group
    const int wv   = wave & 3;
    const int col  = lane & 15;
    const int quad = lane >> 4;
    const int q0   = qblk * 256 + wv * 64;
    const int srow = lane >> 3;
    const int sgr  = lane & 7;

    auto swz = [](int r) { return (r & 7) ^ ((r >> 1) & 4) ^ ((r >> 3) & 2); };

    const ushort_t* Q  = qb_ + (size_t)bh * SEQ * HD;
    const ushort_t* Kp = kb  + (size_t)bh * SEQ * HD;
    const ushort_t* Vt = vtb + (size_t)bh * HD * SEQ;

    ushort_t* Kb0 = &lds[g * 8192];            // this group's K double-buffer
    ushort_t* Vb0 = &lds[16384 + g * 8192];    // this group's V double-buffer

    auto stage = [&](int c, int buf) {
        int kt = c << 6;
        #pragma unroll
        for (int inst = 0; inst < 2; ++inst) {
            int row0 = wv * 16 + inst * 8;
            int r = row0 + srow;
            int gr = sgr ^ swz(r);
            async_copy16(Kp + (size_t)(kt + r) * HD + gr * 8,
                         Kb0 + buf * 4096 + row0 * 64);
            async_copy16(Vt + (size_t)r * SEQ + kt + gr * 8,
                         Vb0 + buf * 4096 + row0 * 64);
        }
    };

    short8 qf[4][2];
    #pragma unroll
    for (int qt = 0; qt < 4; ++qt) {
        qf[qt][0] = *(const short8*)(Q + (size_t)(q0 + qt * 16 + col) * HD + quad * 8);
        qf[qt][1] = *(const short8*)(Q + (size_t)(q0 + qt * 16 + col) * HD + 32 + quad * 8);
    }

    const short8 ones8 = { (short)0x3F80, (short)0x3F80, (short)0x3F80, (short)0x3F80,
                           (short)0x3F80, (short)0x3F80, (short)0x3F80, (short)0x3F80 };

    floatx4 acc[4][4] = {};          // [qt][dt]: row=d (quad*4+reg), col=q (lane&15)
    floatx4 accl[4] = {};            // lsum via ones-MFMA: all rows = sum_k P[k][q]

    stage(g, 0);                // group g starts at chunk g
    __syncthreads();

    for (int i = 0; i < 16; ++i) {
        const int cur = i & 1;
        if (i < 15) stage(2 * (i + 1) + g, cur ^ 1);  // async prefetch, drains at barrier
        const ushort_t* Kc = Kb0 + cur * 4096;
        const ushort_t* Vc = Vb0 + cur * 4096;

        #pragma unroll
        for (int h = 0; h < 2; ++h) {                 // 32-key halves of the 64-key chunk
            short8 kf[2][2], vf8[4];
            #pragma unroll
            for (int nl = 0; nl < 2; ++nl) {
                // interleaved key assignment: tile nl, lane col -> key-in-half
                int krow = h * 32 + ((col >> 2) << 3) + (col & 3) + nl * 4;
                int sk = swz(krow);
                kf[nl][0] = *(const short8*)(Kc + krow * 64 + ((quad ^ sk) * 8));
                kf[nl][1] = *(const short8*)(Kc + krow * 64 + (((4 + quad) ^ sk) * 8));
            }
            #pragma unroll
            for (int dt = 0; dt < 4; ++dt) {
                int vrow = dt * 16 + col;
                vf8[dt] = *(const short8*)(Vc + vrow * 64 + (((h * 4 + quad) ^ swz(vrow)) * 8));
            }
            #pragma unroll
            for (int qt = 0; qt < 4; ++qt) {
                unsigned pk[4];
                #pragma unroll
                for (int nl = 0; nl < 2; ++nl) {
                    floatx4 z = {};
                    __builtin_amdgcn_s_setprio(1);
                    z = __builtin_amdgcn_mfma_f32_16x16x32_bf16(kf[nl][0], qf[qt][0], z, 0, 0, 0);
                    z = __builtin_amdgcn_mfma_f32_16x16x32_bf16(kf[nl][1], qf[qt][1], z, 0, 0, 0);
                    __builtin_amdgcn_s_setprio(0);
                    // Q pre-scaled by QSCALE -> exp2 direct; truncate to bf16.
                    unsigned u0 = __float_as_uint(__builtin_amdgcn_exp2f(z[0]));
                    unsigned u1 = __float_as_uint(__builtin_amdgcn_exp2f(z[1]));
                    unsigned u2 = __float_as_uint(__builtin_amdgcn_exp2f(z[2]));
                    unsigned u3 = __float_as_uint(__builtin_amdgcn_exp2f(z[3]));
                    pk[nl * 2 + 0] = __builtin_amdgcn_perm(u1, u0, 0x07060302u);  // k=8q+{0,1}(+4nl)
                    pk[nl * 2 + 1] = __builtin_amdgcn_perm(u3, u2, 0x07060302u);  // k=8q+{2,3}(+4nl)
                }
                short8 pb8 = *(short8*)pk;       // x32 B-fragment, verbatim (k=quad*8+j)
                __builtin_amdgcn_s_setprio(1);
                accl[qt] = __builtin_amdgcn_mfma_f32_16x16x32_bf16(
                    ones8, pb8, accl[qt], 0, 0, 0);          // lsum in matrix pipe
                #pragma unroll
                for (int dt = 0; dt < 4; ++dt)
                    acc[qt][dt] = __builtin_amdgcn_mfma_f32_16x16x32_bf16(
                        vf8[dt], pb8, acc[qt][dt], 0, 0, 0);
                __builtin_amdgcn_s_setprio(0);
            }
        }
        __syncthreads();   // drains prefetch DMA + all waves' reads of cur buffers
    }

    // ---- cross-group combine: 2 rounds; wave keeps qt {2g, 2g+1} -----------
    // All acc/accl indices are compile-time constants inside wave-uniform
    // if/else arms (rule #20: runtime-indexed ext_vector arrays -> scratch).
    float* fs = (float*)lds;
    const int slot  = (wave * 64 + lane) * 20;    // 8*64*20 floats = 40KB <= 64KB
    const int pslot = ((wave ^ 4) * 64 + lane) * 20;
    floatx4 accK[2][4];
    float lsK[2];
    #pragma unroll
    for (int r2 = 0; r2 < 2; ++r2) {
        if (g == 0) {                                // send qt 2+r2 (partner keeps it)
            #pragma unroll
            for (int d = 0; d < 4; ++d)
                *(floatx4*)(&fs[slot + d * 4]) = (r2 == 0) ? acc[2][d] : acc[3][d];
            fs[slot + 16] = (r2 == 0) ? accl[2][0] : accl[3][0];
        } else {                                     // send qt r2
            #pragma unroll
            for (int d = 0; d < 4; ++d)
                *(floatx4*)(&fs[slot + d * 4]) = (r2 == 0) ? acc[0][d] : acc[1][d];
            fs[slot + 16] = (r2 == 0) ? accl[0][0] : accl[1][0];
        }
        __syncthreads();
        if (g == 0) {                                // keep qt r2
            #pragma unroll
            for (int d = 0; d < 4; ++d)
                accK[r2][d] = ((r2 == 0) ? acc[0][d] : acc[1][d])
                            + *(const floatx4*)(&fs[pslot + d * 4]);
            lsK[r2] = ((r2 == 0) ? accl[0][0] : accl[1][0]) + fs[pslot + 16];
        } else {                                     // keep qt 2+r2
            #pragma unroll
            for (int d = 0; d < 4; ++d)
                accK[r2][d] = ((r2 == 0) ? acc[2][d] : acc[3][d])
                            + *(const floatx4*)(&fs[pslot + d * 4]);
            lsK[r2] = ((r2 == 0) ? accl[2][0] : accl[3][0]) + fs[pslot + 16];
        }
        __syncthreads();
    }

    int b = bh >> 4, hh = bh & 15;
    #pragma unroll
    for (int r2 = 0; r2 < 2; ++r2) {
        float inv = 1.0f / lsK[r2];                  // q = lane&15 for every acc element
        int row = q0 + (2 * g + r2) * 16 + col;
        #pragma unroll
        for (int dt = 0; dt < 4; ++dt) {
            short4v o;
            o.x = (short)f2bf(accK[r2][dt][0] * inv);
            o.y = (short)f2bf(accK[r2][dt][1] * inv);
            o.z = (short)f2bf(accK[r2][dt][2] * inv);
            o.w = (short)f2bf(accK[r2][dt][3] * inv);
            *(short4v*)(attn + ((size_t)b * SEQ + row) * EMBED + hh * HD + dt * 16 + quad * 4) = o;
        }
    }
}

// ---------------- launch ----------------
extern "C" void kernel_launch(void* const* d_in, const int* in_sizes, int n_in,
                              void* d_out, int out_size, void* d_ws, size_t ws_size,
                              hipStream_t stream) {
    const float* x     = (const float*)d_in[0];   // [2,2048,1024]
    const float* w_qkv = (const float*)d_in[1];   // [3072,1024]
    const float* w_out = (const float*)d_in[2];   // [1024,1024]
    float* out = (float*)d_out;                   // [2,2048,1024] fp32

    char* ws = (char*)d_ws;
    size_t off = 0;
    ushort_t* x_bf    = (ushort_t*)(ws + off); off += (size_t)BATCH * SEQ * EMBED * 2;
    ushort_t* wqkv_bf = (ushort_t*)(ws + off); off += (size_t)3 * EMBED * EMBED * 2;
    ushort_t* wout_bf = (ushort_t*)(ws + off); off += (size_t)EMBED * EMBED * 2;
    ushort_t* q_buf   = (ushort_t*)(ws + off); off += (size_t)BATCH * HEADS * SEQ * HD * 2;
    ushort_t* k_buf   = (ushort_t*)(ws + off); off += (size_t)BATCH * HEADS * SEQ * HD * 2;
    ushort_t* vt_buf  = (ushort_t*)(ws + off); off += (size_t)BATCH * HEADS * SEQ * HD * 2;
    ushort_t* attn_bf = (ushort_t*)(ws + off); off += (size_t)BATCH * SEQ * EMBED * 2;

    int n_x = BATCH * SEQ * EMBED, n_wq = 3 * EMBED * EMBED, n_wo = EMBED * EMBED;
    int n_all = n_x + n_wq + n_wo;
    cast3_kernel<<<n_all / 1024, 256, 0, stream>>>(x, x_bf, n_x, w_qkv, wqkv_bf, n_wq,
                                                   w_out, wout_bf, n_wo);

    // qkv = x @ w_qkv^T : M=4096, N=3072, K=1024 -> 32x24 = 768 blocks
    gemm_bt<0, 128><<<768, 256, 0, stream>>>(
        x_bf, wqkv_bf, nullptr, q_buf, k_buf, vt_buf, BATCH * SEQ, 3 * EMBED, EMBED);

    attn_kernel<<<256, 512, 0, stream>>>(q_buf, k_buf, vt_buf, attn_bf);

    // out = attn @ w_out^T : M=4096, N=1024, K=1024 -> 32x16 = 512 blocks (2/CU)
    gemm_bt<1, 64><<<512, 256, 0, stream>>>(
        attn_bf, wout_bf, out, nullptr, nullptr, nullptr, BATCH * SEQ, EMBED, EMBED);
}

// Round 8
// 160.558 us; speedup vs baseline: 2.3909x; 1.0305x over previous
//
#include <hip/hip_runtime.h>

typedef short short8 __attribute__((ext_vector_type(8)));
typedef short short4v __attribute__((ext_vector_type(4)));
typedef float floatx4 __attribute__((ext_vector_type(4)));
typedef unsigned short ushort_t;

#define EMBED 1024
#define HEADS 16
#define HD 64
#define SEQ 2048
#define BATCH 2
#define QSCALE 0.18033688f   // log2(e) / sqrt(64), folded into Q at GEMM epilogue

__device__ inline ushort_t f2bf(float f) {
    unsigned int u = __float_as_uint(f);
    u += 0x7fff + ((u >> 16) & 1);   // round-to-nearest-even
    return (ushort_t)(u >> 16);
}

// async global->LDS, 16B per lane. LDS dest = wave-uniform base + lane*16.
typedef const __attribute__((address_space(1))) unsigned int* gas_t;
typedef __attribute__((address_space(3))) unsigned int* las_t;
__device__ inline void async_copy16(const ushort_t* g, ushort_t* l) {
    __builtin_amdgcn_global_load_lds((gas_t)g, (las_t)l, 16, 0, 0);
}

// ---------------- fused cast fp32 -> bf16 (3 tensors, 1 launch) -----------
__global__ void cast3_kernel(const float* __restrict__ a, ushort_t* __restrict__ oa, int na,
                             const float* __restrict__ b, ushort_t* __restrict__ ob, int nb,
                             const float* __restrict__ c, ushort_t* __restrict__ oc, int nc) {
    int idx = (blockIdx.x * blockDim.x + threadIdx.x) * 4;
    const float* in; ushort_t* out;
    if (idx < na)            { in = a;  out = oa; }
    else if (idx < na + nb)  { in = b;  out = ob; idx -= na; }
    else if (idx < na + nb + nc) { in = c; out = oc; idx -= na + nb; }
    else return;
    float4 f = *(const float4*)(in + idx);
    ushort4 o;
    o.x = f2bf(f.x); o.y = f2bf(f.y); o.z = f2bf(f.z); o.w = f2bf(f.w);
    *(ushort4*)(out + idx) = o;
}

// ---------------- GEMM (BK=64, XCD swizzle): Y = A * B^T ------------------
// TBN=128 for the big QKV GEMM; TBN=64 for the out-proj (512 blocks = 2/CU).
#define BM 128
#define BK 64

template<int MODE, int TBN>
__launch_bounds__(256, 3)
__global__ void gemm_bt(const ushort_t* __restrict__ A, const ushort_t* __restrict__ B,
                        float* __restrict__ outF,
                        ushort_t* __restrict__ qb, ushort_t* __restrict__ kb,
                        ushort_t* __restrict__ vtb,
                        int M, int N, int K) {
    __shared__ ushort_t As[BM * BK];    // 16KB, unpadded (DMA dest), XOR-swizzled granules
    __shared__ ushort_t Bs[TBN * BK];   // 16KB or 8KB
    const int id   = blockIdx.x;
    const int jj   = id >> 3;
    const int bm   = (id & 7) * 4 + (jj & 3);   // 4 m-blocks per XCD
    const int bn   = jj >> 2;
    const int t    = threadIdx.x;
    const int lane = t & 63;
    const int wave = t >> 6;
    const int wm   = (wave >> 1) * 64;
    const int wn   = (wave & 1) * (TBN / 2);
    const int m0   = bm * BM;
    const int n0   = bn * TBN;
    const int col  = lane & 15;
    const int quad = lane >> 4;
    constexpr int NJ = TBN / 32;

    const int srow = lane >> 3;
    const int sgr  = (lane & 7) ^ (srow & 7);
    const int slot0 = quad ^ (col & 7);          // granules 0..3  (k 0..31)

    floatx4 acc[4][NJ] = {};

    for (int k0 = 0; k0 < K; k0 += BK) {
        for (int half = 0; half < 4; ++half) {
            int row0 = wave * 32 + half * 8;
            int r = row0 + srow;
            async_copy16(A + (size_t)(m0 + r) * K + k0 + sgr * 8, &As[row0 * BK]);
        }
        for (int half = 0; half < TBN / 32; ++half) {
            int row0 = wave * (TBN / 4) + half * 8;
            int r = row0 + srow;
            async_copy16(B + (size_t)(n0 + r) * K + k0 + sgr * 8, &Bs[row0 * BK]);
        }
        __syncthreads();
        short8 a[2][4], b[2][NJ];
        for (int i = 0; i < 4; ++i) {
            int base = (wm + i * 16 + col) * BK;
            a[0][i] = *(const short8*)(&As[base + slot0 * 8]);
            a[1][i] = *(const short8*)(&As[base + (slot0 ^ 4) * 8]);
        }
        for (int j = 0; j < NJ; ++j) {
            int base = (wn + j * 16 + col) * BK;
            b[0][j] = *(const short8*)(&Bs[base + slot0 * 8]);
            b[1][j] = *(const short8*)(&Bs[base + (slot0 ^ 4) * 8]);
        }
        for (int kk = 0; kk < 2; ++kk)
            for (int i = 0; i < 4; ++i)
                for (int j = 0; j < NJ; ++j)
                    acc[i][j] = __builtin_amdgcn_mfma_f32_16x16x32_bf16(a[kk][i], b[kk][j], acc[i][j], 0, 0, 0);
        __syncthreads();
    }

    for (int i = 0; i < 4; ++i)
        for (int j = 0; j < NJ; ++j) {
            int n = n0 + wn + j * 16 + col;
            int mb = m0 + wm + i * 16 + quad * 4;   // 4 consecutive m
            if (MODE == 1) {
                for (int r = 0; r < 4; ++r)
                    outF[(size_t)(mb + r) * N + n] = acc[i][j][r];
            } else {
                int part = n >> 10;          // 0=q 1=k 2=v
                int within = n & 1023;
                int h = within >> 6, d = within & 63;
                int bb = mb >> 11, s = mb & 2047;
                if (part == 2) {
                    short4v pv;
                    pv.x = (short)f2bf(acc[i][j][0]); pv.y = (short)f2bf(acc[i][j][1]);
                    pv.z = (short)f2bf(acc[i][j][2]); pv.w = (short)f2bf(acc[i][j][3]);
                    *(short4v*)(vtb + (((size_t)bb * HEADS + h) * HD + d) * SEQ + s) = pv;
                } else {
                    ushort_t* dst = (part == 0) ? qb : kb;
                    const float scl = (part == 0) ? QSCALE : 1.0f;  // pre-scale Q
                    for (int r = 0; r < 4; ++r)
                        dst[(((size_t)bb * HEADS + h) * SEQ + s + r) * HD + d] = f2bf(acc[i][j][r] * scl);
                }
            }
        }
}

// ---------------- flash-style attention v11: full-rate x32 PV -------------
// (reverted to the R5-verified best: 42.7 us. v12/v12b's 64q-per-wave
// geometry was a measured loss: register footprint caps this math shape at
// 4 waves/SIMD, so halving blocks halves TLP without a compensating gain.)
// 512 x 512, 2 kt-groups of 4 waves, 32q/wave, 64-key chunks. The two
// 16-key QK^T tiles of each 32-key half hold keys interleaved in 4-nibbles:
// tile nl, row m <-> key (m>>2)*8 + (m&3) + nl*4. Lane-quad q then gets
// keys 8q+0..3 (nl=0) and 8q+4..7 (nl=1), so the two packed pk pairs
// concatenate into a verbatim 16x16x32 B-fragment (k = quad*8+j): PV and
// lsum run as full-rate x32 MFMAs, V fragments are contiguous 16B reads.
// Stage/read swizzle swz(r) = (r&7)^((r>>1)&4)^((r>>3)&2) keeps both the
// interleaved kf pattern and the V pattern at 2-way (free) bank aliasing.
// LDS 64KB: K[2grp][2buf][64x64] 32K + V[2grp][2buf][64x64] 32K.
__launch_bounds__(512, 4)
__global__ void attn_kernel(const ushort_t* __restrict__ qb_, const ushort_t* __restrict__ kb,
                            const ushort_t* __restrict__ vtb, ushort_t* __restrict__ attn) {
    __shared__ __align__(16) ushort_t lds[32768];  // 64KB
    const int id   = blockIdx.x;             // 512 blocks
    const int jj   = id >> 3;                // 0..63
    const int bh   = (id & 7) * 4 + (jj >> 4);
    const int qblk = jj & 15;
    const int t    = threadIdx.x;
    const int lane = t & 63;
    const int wave = t >> 6;                 // 0..7
    const int g    = wave >> 2;              // kt group
    const int wv   = wave & 3;
    const int col  = lane & 15;
    const int quad = lane >> 4;
    const int q0   = qblk * 128 + wv * 32;
    const int srow = lane >> 3;
    const int sgr  = lane & 7;

    auto swz = [](int r) { return (r & 7) ^ ((r >> 1) & 4) ^ ((r >> 3) & 2); };

    const ushort_t* Q  = qb_ + (size_t)bh * SEQ * HD;
    const ushort_t* Kp = kb  + (size_t)bh * SEQ * HD;
    const ushort_t* Vt = vtb + (size_t)bh * HD * SEQ;

    ushort_t* Kb0 = &lds[g * 8192];            // this group's K double-buffer
    ushort_t* Vb0 = &lds[16384 + g * 8192];    // this group's V double-buffer

    auto stage = [&](int c, int buf) {
        int kt = c << 6;
        #pragma unroll
        for (int inst = 0; inst < 2; ++inst) {
            int row0 = wv * 16 + inst * 8;
            int r = row0 + srow;
            int gr = sgr ^ swz(r);
            async_copy16(Kp + (size_t)(kt + r) * HD + gr * 8,
                         Kb0 + buf * 4096 + row0 * 64);
            async_copy16(Vt + (size_t)r * SEQ + kt + gr * 8,
                         Vb0 + buf * 4096 + row0 * 64);
        }
    };

    short8 qf[2][2];
    #pragma unroll
    for (int qt = 0; qt < 2; ++qt) {
        qf[qt][0] = *(const short8*)(Q + (size_t)(q0 + qt * 16 + col) * HD + quad * 8);
        qf[qt][1] = *(const short8*)(Q + (size_t)(q0 + qt * 16 + col) * HD + 32 + quad * 8);
    }

    const short8 ones8 = { (short)0x3F80, (short)0x3F80, (short)0x3F80, (short)0x3F80,
                           (short)0x3F80, (short)0x3F80, (short)0x3F80, (short)0x3F80 };

    floatx4 acc[2][4] = {};          // [qt][dt]: row=d (quad*4+reg), col=q (lane&15)
    floatx4 accl[2] = {};            // lsum via ones-MFMA: all rows = sum_k P[k][q]

    stage(g, 0);                // group g starts at chunk g
    __syncthreads();

    for (int i = 0; i < 16; ++i) {
        const int cur = i & 1;
        if (i < 15) stage(2 * (i + 1) + g, cur ^ 1);  // async prefetch, drains at barrier
        const ushort_t* Kc = Kb0 + cur * 4096;
        const ushort_t* Vc = Vb0 + cur * 4096;

        #pragma unroll
        for (int h = 0; h < 2; ++h) {                 // 32-key halves of the 64-key chunk
            short8 kf[2][2], vf8[4];
            #pragma unroll
            for (int nl = 0; nl < 2; ++nl) {
                // interleaved key assignment: tile nl, lane col -> key-in-half
                int krow = h * 32 + ((col >> 2) << 3) + (col & 3) + nl * 4;
                int sk = swz(krow);
                kf[nl][0] = *(const short8*)(Kc + krow * 64 + ((quad ^ sk) * 8));
                kf[nl][1] = *(const short8*)(Kc + krow * 64 + (((4 + quad) ^ sk) * 8));
            }
            #pragma unroll
            for (int dt = 0; dt < 4; ++dt) {
                int vrow = dt * 16 + col;
                vf8[dt] = *(const short8*)(Vc + vrow * 64 + (((h * 4 + quad) ^ swz(vrow)) * 8));
            }
            #pragma unroll
            for (int qt = 0; qt < 2; ++qt) {
                unsigned pk[4];
                #pragma unroll
                for (int nl = 0; nl < 2; ++nl) {
                    floatx4 z = {};
                    __builtin_amdgcn_s_setprio(1);
                    z = __builtin_amdgcn_mfma_f32_16x16x32_bf16(kf[nl][0], qf[qt][0], z, 0, 0, 0);
                    z = __builtin_amdgcn_mfma_f32_16x16x32_bf16(kf[nl][1], qf[qt][1], z, 0, 0, 0);
                    __builtin_amdgcn_s_setprio(0);
                    // Q pre-scaled by QSCALE -> exp2 direct; truncate to bf16.
                    unsigned u0 = __float_as_uint(__builtin_amdgcn_exp2f(z[0]));
                    unsigned u1 = __float_as_uint(__builtin_amdgcn_exp2f(z[1]));
                    unsigned u2 = __float_as_uint(__builtin_amdgcn_exp2f(z[2]));
                    unsigned u3 = __float_as_uint(__builtin_amdgcn_exp2f(z[3]));
                    pk[nl * 2 + 0] = __builtin_amdgcn_perm(u1, u0, 0x07060302u);  // k=8q+{0,1}(+4nl)
                    pk[nl * 2 + 1] = __builtin_amdgcn_perm(u3, u2, 0x07060302u);  // k=8q+{2,3}(+4nl)
                }
                short8 pb8 = *(short8*)pk;       // x32 B-fragment, verbatim (k=quad*8+j)
                __builtin_amdgcn_s_setprio(1);
                accl[qt] = __builtin_amdgcn_mfma_f32_16x16x32_bf16(
                    ones8, pb8, accl[qt], 0, 0, 0);          // lsum in matrix pipe
                #pragma unroll
                for (int dt = 0; dt < 4; ++dt)
                    acc[qt][dt] = __builtin_amdgcn_mfma_f32_16x16x32_bf16(
                        vf8[dt], pb8, acc[qt][dt], 0, 0, 0);
                __builtin_amdgcn_s_setprio(0);
            }
        }
        __syncthreads();   // drains prefetch DMA + all waves' reads of cur buffers
    }

    float lsum[2] = { accl[0][0], accl[1][0] };   // full key-sum, per q-column

    // ---- cross-group combine: exchange the qt tile the partner will emit ----
    float* fs = (float*)lds;
    const int slot = (wave * 64 + lane) * 20;     // 8*64*20 floats = 40KB <= 64KB
    floatx4 accK[4];
    float lsK;
    if (g == 0) {
        #pragma unroll
        for (int d = 0; d < 4; ++d) { *(floatx4*)(&fs[slot + d * 4]) = acc[1][d]; accK[d] = acc[0][d]; }
        fs[slot + 16] = lsum[1]; lsK = lsum[0];
    } else {
        #pragma unroll
        for (int d = 0; d < 4; ++d) { *(floatx4*)(&fs[slot + d * 4]) = acc[0][d]; accK[d] = acc[1][d]; }
        fs[slot + 16] = lsum[0]; lsK = lsum[1];
    }
    __syncthreads();
    const int pslot = ((wave ^ 4) * 64 + lane) * 20;
    #pragma unroll
    for (int d = 0; d < 4; ++d)
        accK[d] += *(const floatx4*)(&fs[pslot + d * 4]);
    float s = lsK + fs[pslot + 16];               // already summed over all keys
    float inv = 1.0f / s;                         // q = lane&15 for every acc element

    int b = bh >> 4, hh = bh & 15;
    int row = q0 + g * 16 + col;                  // wave emits its own-group qt tile
    #pragma unroll
    for (int dt = 0; dt < 4; ++dt) {
        short4v o;
        o.x = (short)f2bf(accK[dt][0] * inv);
        o.y = (short)f2bf(accK[dt][1] * inv);
        o.z = (short)f2bf(accK[dt][2] * inv);
        o.w = (short)f2bf(accK[dt][3] * inv);
        *(short4v*)(attn + ((size_t)b * SEQ + row) * EMBED + hh * HD + dt * 16 + quad * 4) = o;
    }
}

// ---------------- launch ----------------
extern "C" void kernel_launch(void* const* d_in, const int* in_sizes, int n_in,
                              void* d_out, int out_size, void* d_ws, size_t ws_size,
                              hipStream_t stream) {
    const float* x     = (const float*)d_in[0];   // [2,2048,1024]
    const float* w_qkv = (const float*)d_in[1];   // [3072,1024]
    const float* w_out = (const float*)d_in[2];   // [1024,1024]
    float* out = (float*)d_out;                   // [2,2048,1024] fp32

    char* ws = (char*)d_ws;
    size_t off = 0;
    ushort_t* x_bf    = (ushort_t*)(ws + off); off += (size_t)BATCH * SEQ * EMBED * 2;
    ushort_t* wqkv_bf = (ushort_t*)(ws + off); off += (size_t)3 * EMBED * EMBED * 2;
    ushort_t* wout_bf = (ushort_t*)(ws + off); off += (size_t)EMBED * EMBED * 2;
    ushort_t* q_buf   = (ushort_t*)(ws + off); off += (size_t)BATCH * HEADS * SEQ * HD * 2;
    ushort_t* k_buf   = (ushort_t*)(ws + off); off += (size_t)BATCH * HEADS * SEQ * HD * 2;
    ushort_t* vt_buf  = (ushort_t*)(ws + off); off += (size_t)BATCH * HEADS * SEQ * HD * 2;
    ushort_t* attn_bf = (ushort_t*)(ws + off); off += (size_t)BATCH * SEQ * EMBED * 2;

    int n_x = BATCH * SEQ * EMBED, n_wq = 3 * EMBED * EMBED, n_wo = EMBED * EMBED;
    int n_all = n_x + n_wq + n_wo;
    cast3_kernel<<<n_all / 1024, 256, 0, stream>>>(x, x_bf, n_x, w_qkv, wqkv_bf, n_wq,
                                                   w_out, wout_bf, n_wo);

    // qkv = x @ w_qkv^T : M=4096, N=3072, K=1024 -> 32x24 = 768 blocks
    gemm_bt<0, 128><<<768, 256, 0, stream>>>(
        x_bf, wqkv_bf, nullptr, q_buf, k_buf, vt_buf, BATCH * SEQ, 3 * EMBED, EMBED);

    attn_kernel<<<512, 512, 0, stream>>>(q_buf, k_buf, vt_buf, attn_bf);

    // out = attn @ w_out^T : M=4096, N=1024, K=1024 -> 32x16 = 512 blocks (2/CU)
    gemm_bt<1, 64><<<512, 256, 0, stream>>>(
        attn_bf, wout_bf, out, nullptr, nullptr, nullptr, BATCH * SEQ, EMBED, EMBED);
}